// Round 6
// baseline (648.547 us; speedup 1.0000x reference)
//
#include <hip/hip_runtime.h>
#include <math.h>

#define BATCH 256
#define NPTS  16384
#define TPB   256
#define MID_TPB 1024

// pass1 tiling: grid (BATCH, P1_CHUNKS); 4 waves/block; wave handles 512 pts
#define P1_CHUNKS     8
#define P1_PTS_BLOCK  (NPTS / P1_CHUNKS)      // 2048
#define P1_ITERS      8                        // 8 iters x 64 pts = 512 pts/wave

// ---- workspace: per-(batch,chunk) partials, stride 256 floats ----
// [0..63] chMax, [64..127] chSum, [128..191] chSumSq, [192..200] moments
#define PART_STRIDE 256

typedef __bf16 bf16x8  __attribute__((ext_vector_type(8)));
typedef float  floatx4 __attribute__((ext_vector_type(4)));
typedef float  floatx2 __attribute__((ext_vector_type(2)));

// ---------------- pass 1: coord moments + MFMA point-MLP + channel stats ----------------
// A-frag (16x16x32 bf16): A[m = lane&15][k = (lane>>4)*8 + j]
// B-frag:                 B[k = (lane>>4)*8 + j][n = lane&15]
// C/D layout:             col = lane&15, row = (lane>>4)*4 + reg   [m89]
// R11 (post-mortem of R10: rolled prefetch + deferred-relu = real but small,
// 65->62us, no spill; VALUBusy still ~60% => ~40% issue slots idle with
// MfmaUtil 10.5 and only ~2.7 waves/SIMD resident (Occupancy 34%)):
//  - NEW (single variable): __launch_bounds__(256, 8) — 8 blocks/CU =
//    32 waves/CU, double the previous 4-block cap. Kernel resources allow
//    it: VGPR 60 (8x60=480<=512), LDS 3584B x 8 = 28KB << 160KB, grid
//    2048 = 256CU x 8. 2x TLP to cover the shfl-lgkm/MFMA/load stalls.
//  - KEPT: rolled depth-1 prefetch (R10: -3us), deferred-relu raw max
//    (R10), biasC-as-C-operand (R6), packed add/fma stats (R8), shfl sem
//    broadcast (R6 regression proved direct loads worse).
// NOTE: all arrays constant-indexed (R3 lesson). Spill signature =
// WRITE_SIZE jump above ~1.7 MB; the 8-wave bound caps VGPR at 64 (we use
// 60) so codegen pressure is unchanged.
// NOTE2 (R5): do NOT fuse the mid phase in via per-block __threadfence()
// election — device-scope fences are L2 writeback/invalidate ops on gfx950
// and serialized the whole dispatch (63 -> 357 us).
__global__ __launch_bounds__(TPB, 8)
void pass1_kernel(const float* __restrict__ x, const float* __restrict__ W1,
                  const float* __restrict__ b1, const float* __restrict__ W2,
                  const float* __restrict__ b2, float* __restrict__ ws) {
    const int b     = blockIdx.x;
    const int chunk = blockIdx.y;
    const int tid   = threadIdx.x;
    const int lane  = tid & 63;
    const int wave  = tid >> 6;
    const int quad  = lane >> 4;
    const int l15   = lane & 15;

    // W2 (32x64) as 4 B-frags (16-channel tiles); bias folded into C frags
    bf16x8  Bf[4];
    floatx4 biasC[4];
#pragma unroll
    for (int t = 0; t < 4; ++t) {
        int n = t * 16 + l15;
#pragma unroll
        for (int j = 0; j < 8; ++j)
            Bf[t][j] = (__bf16)W2[(quad * 8 + j) * 64 + n];
        float bb = b2[n];
        biasC[t] = (floatx4){bb, bb, bb, bb};
    }
    // layer-1 weights for this lane's k-range (k = quad*8 + j), as f32 pairs
    floatx2 w1a2[4], w1b2[4], b1r2[4];
#pragma unroll
    for (int jp = 0; jp < 4; ++jp) {
        int jj = quad * 8 + jp * 2;
        w1a2[jp] = (floatx2){W1[jj],      W1[jj + 1]};
        w1b2[jp] = (floatx2){W1[32 + jj], W1[32 + jj + 1]};
        b1r2[jp] = (floatx2){b1[jj],      b1[jj + 1]};
    }

    const floatx2 zero2 = {0.f, 0.f};
    float   vmaxr[4] = {0.f, 0.f, 0.f, 0.f};   // raw max, init 0 == deferred relu
    floatx2 vsum[4], vsq[4];
#pragma unroll
    for (int t = 0; t < 4; ++t) {
        vsum[t] = zero2;
        vsq[t]  = zero2;
    }
    float mo[9];
#pragma unroll
    for (int j = 0; j < 9; ++j) mo[j] = 0.f;

    const float* xb = x + ((size_t)b * NPTS + (size_t)chunk * P1_PTS_BLOCK) * 5;
    const float* pc = xb + (size_t)wave * (P1_ITERS * 64) * 5 + (size_t)lane * 5;

    // depth-1 rolled software pipeline
    float c0 = pc[0], c1 = pc[1], c2 = pc[2], s0 = pc[3], s1 = pc[4];

#pragma unroll 1
    for (int it = 0; it < P1_ITERS; ++it) {
        // prefetch it+1 (wave-uniform clamp on last iter: harmless re-read)
        const float* pn = pc + ((it < P1_ITERS - 1) ? 320 : 0);
        float n0 = pn[0], n1 = pn[1], n2 = pn[2], n3 = pn[3], n4 = pn[4];

        mo[0] += c0; mo[1] += c1; mo[2] += c2;
        mo[3] = fmaf(c0, c0, mo[3]); mo[4] = fmaf(c0, c1, mo[4]); mo[5] = fmaf(c0, c2, mo[5]);
        mo[6] = fmaf(c1, c1, mo[6]); mo[7] = fmaf(c1, c2, mo[7]); mo[8] = fmaf(c2, c2, mo[8]);

#pragma unroll
        for (int g = 0; g < 4; ++g) {
            int src = g * 16 + l15;
            float gs0 = __shfl(s0, src);
            float gs1 = __shfl(s1, src);
            floatx2 G0 = {gs0, gs0}, G1 = {gs1, gs1};
            bf16x8 Af;
#pragma unroll
            for (int jp = 0; jp < 4; ++jp) {
                floatx2 h = __builtin_elementwise_fma(
                    G0, w1a2[jp], __builtin_elementwise_fma(G1, w1b2[jp], b1r2[jp]));
                h = __builtin_elementwise_max(h, zero2);
                Af[2 * jp]     = (__bf16)h[0];
                Af[2 * jp + 1] = (__bf16)h[1];
            }
#pragma unroll
            for (int t = 0; t < 4; ++t) {
                // D != C: biasC stays live, no per-MFMA C-init movs
                floatx4 D = __builtin_amdgcn_mfma_f32_16x16x32_bf16(Af, Bf[t], biasC[t], 0, 0, 0);
                // raw max chain (v_max3 fusable), relu deferred via init 0
                vmaxr[t] = fmaxf(fmaxf(D[0], D[1]),
                                 fmaxf(fmaxf(D[2], D[3]), vmaxr[t]));
                floatx2 d01 = {D[0], D[1]}, d23 = {D[2], D[3]};
                floatx2 p01 = __builtin_elementwise_max(d01, zero2); // relu for sum/sq
                floatx2 p23 = __builtin_elementwise_max(d23, zero2);
                vsum[t] += p01 + p23;                                // v_pk_add_f32
                vsq[t]   = __builtin_elementwise_fma(p01, p01,       // v_pk_fma_f32
                               __builtin_elementwise_fma(p23, p23, vsq[t]));
            }
        }

        // rotate pipeline registers
        c0 = n0; c1 = n1; c2 = n2; s0 = n3; s1 = n4;
        pc += 320;   // 64 points * 5 floats
    }

    // finalize packed accumulators, then combine quads (lanes sharing l15)
    float vmax[4], vs[4], vq[4];
#pragma unroll
    for (int t = 0; t < 4; ++t) {
        vmax[t] = vmaxr[t];                    // == max over relu'd (init 0)
        vs[t]   = vsum[t][0] + vsum[t][1];
        vq[t]   = vsq[t][0] + vsq[t][1];
        vmax[t] = fmaxf(vmax[t], __shfl_xor(vmax[t], 16));
        vmax[t] = fmaxf(vmax[t], __shfl_xor(vmax[t], 32));
        vs[t] += __shfl_xor(vs[t], 16);
        vs[t] += __shfl_xor(vs[t], 32);
        vq[t] += __shfl_xor(vq[t], 16);
        vq[t] += __shfl_xor(vq[t], 32);
    }
#pragma unroll
    for (int j = 0; j < 9; ++j) {
        float v = mo[j];
#pragma unroll
        for (int o = 32; o > 0; o >>= 1) v += __shfl_xor(v, o);
        mo[j] = v;
    }

    __shared__ float red[4][201];
    if (quad == 0) {
#pragma unroll
        for (int t = 0; t < 4; ++t) {
            red[wave][t * 16 + l15]       = vmax[t];
            red[wave][64 + t * 16 + l15]  = vs[t];
            red[wave][128 + t * 16 + l15] = vq[t];
        }
    }
    if (lane == 0) {
#pragma unroll
        for (int j = 0; j < 9; ++j) red[wave][192 + j] = mo[j];
    }
    __syncthreads();

    // non-atomic partial write: slot (b*P1_CHUNKS + chunk)
    if (tid < 201) {
        float v0 = red[0][tid], v1 = red[1][tid], v2 = red[2][tid], v3 = red[3][tid];
        float r = (tid < 64) ? fmaxf(fmaxf(v0, v1), fmaxf(v2, v3))
                             : (v0 + v1) + (v2 + v3);
        ws[(size_t)(b * P1_CHUNKS + chunk) * PART_STRIDE + tid] = r;
    }
}

// ---------------- fused mid: reduce partials + eigh + extents + final MLP ----------------
// 1024 threads: 16 waves for the latency-bound extents scan; MLP layers use
// split-K partial sums across the extra waves.
__global__ __launch_bounds__(MID_TPB)
void mid_kernel(const float* __restrict__ x,
                const float* __restrict__ W3, const float* __restrict__ b3,
                const float* __restrict__ W4, const float* __restrict__ b4,
                const float* __restrict__ W5, const float* __restrict__ b5,
                const float* __restrict__ ws, float* __restrict__ out) {
    const int b = blockIdx.x, t = threadIdx.x;
    const int lane = t & 63, wave = t >> 6;

    __shared__ float comb[201];
    __shared__ float eg[15];        // [0..8] evecs, [9..11] eig_norm, [12..14] centroid
    __shared__ float redmm[16][8];
    __shared__ float g[224];
    __shared__ float h1[256];
    __shared__ float h2[128];
    __shared__ float part[8][256];  // split-K partial sums

    // --- reduce the 8 per-chunk partials ---
    if (t < 201) {
        const float* base = ws + (size_t)b * P1_CHUNKS * PART_STRIDE + t;
        float acc = base[0];
        if (t < 64) {
#pragma unroll
            for (int i = 1; i < P1_CHUNKS; ++i) acc = fmaxf(acc, base[i * PART_STRIDE]);
        } else {
#pragma unroll
            for (int i = 1; i < P1_CHUNKS; ++i) acc += base[i * PART_STRIDE];
        }
        comb[t] = acc;
    }
    __syncthreads();

    // --- fp32 Jacobi eigh (thread 0) ---
    if (t == 0) {
        const float n = (float)NPTS;
        float mx = comb[192] / n, my = comb[193] / n, mz = comb[194] / n;
        float A[3][3];
        A[0][0] = comb[195] / n - mx * mx; A[0][1] = comb[196] / n - mx * my;
        A[0][2] = comb[197] / n - mx * mz;
        A[1][1] = comb[198] / n - my * my; A[1][2] = comb[199] / n - my * mz;
        A[2][2] = comb[200] / n - mz * mz;
        A[1][0] = A[0][1]; A[2][0] = A[0][2]; A[2][1] = A[1][2];
        float V[3][3] = {{1, 0, 0}, {0, 1, 0}, {0, 0, 1}};
        const int PP[3] = {0, 0, 1};
        const int QQ[3] = {1, 2, 2};
        for (int sweep = 0; sweep < 7; ++sweep) {
            for (int r3 = 0; r3 < 3; ++r3) {
                int p = PP[r3], q = QQ[r3];
                float apq = A[p][q];
                if (fabsf(apq) < 1e-35f) continue;
                float theta = (A[q][q] - A[p][p]) / (2.0f * apq);
                float tt = 1.0f / (fabsf(theta) + sqrtf(fmaf(theta, theta, 1.0f)));
                if (theta < 0.0f) tt = -tt;
                float c = 1.0f / sqrtf(fmaf(tt, tt, 1.0f)), s = tt * c;
                float apq_t = tt * apq;
                A[p][p] -= apq_t;
                A[q][q] += apq_t;
                A[p][q] = A[q][p] = 0.0f;
                for (int r = 0; r < 3; ++r) {
                    if (r != p && r != q) {
                        float arp = A[r][p], arq = A[r][q];
                        A[r][p] = A[p][r] = c * arp - s * arq;
                        A[r][q] = A[q][r] = s * arp + c * arq;
                    }
                    float vrp = V[r][p], vrq = V[r][q];
                    V[r][p] = c * vrp - s * vrq;
                    V[r][q] = s * vrp + c * vrq;
                }
            }
        }
        float w[3] = {A[0][0], A[1][1], A[2][2]};
        int i0 = 0, i1 = 1, i2 = 2, sw;
        if (w[i0] < w[i1]) { sw = i0; i0 = i1; i1 = sw; }
        if (w[i0] < w[i2]) { sw = i0; i0 = i2; i2 = sw; }
        if (w[i1] < w[i2]) { sw = i1; i1 = i2; i2 = sw; }
        int idx[3] = {i0, i1, i2};
        for (int e = 0; e < 3; ++e)
            for (int comp = 0; comp < 3; ++comp)
                eg[e * 3 + comp] = V[comp][idx[e]];
        float sum = w[0] + w[1] + w[2] + 1e-8f;
        for (int e = 0; e < 3; ++e) eg[9 + e] = w[idx[e]] / sum;
        eg[12] = mx; eg[13] = my; eg[14] = mz;
    }
    __syncthreads();

    // --- projection extents over this batch's 16384 points (16 waves) ---
    float e0x = eg[0], e0y = eg[1], e0z = eg[2];
    float e1x = eg[3], e1y = eg[4], e1z = eg[5];
    float e2x = eg[6], e2y = eg[7], e2z = eg[8];
    float cx = eg[12], cy = eg[13], cz = eg[14];

    const float* xb = x + (size_t)b * NPTS * 5;
    float mn[3] = {3.4e38f, 3.4e38f, 3.4e38f};
    float mx3[3] = {-3.4e38f, -3.4e38f, -3.4e38f};
#pragma unroll 4
    for (int i = 0; i < NPTS / MID_TPB; ++i) {
        const float* p = xb + (size_t)(i * MID_TPB + t) * 5;
        float c0 = p[0] - cx, c1 = p[1] - cy, c2 = p[2] - cz;
        float p0 = fmaf(c0, e0x, fmaf(c1, e0y, c2 * e0z));
        float p1 = fmaf(c0, e1x, fmaf(c1, e1y, c2 * e1z));
        float p2 = fmaf(c0, e2x, fmaf(c1, e2y, c2 * e2z));
        mn[0] = fminf(mn[0], p0); mx3[0] = fmaxf(mx3[0], p0);
        mn[1] = fminf(mn[1], p1); mx3[1] = fmaxf(mx3[1], p1);
        mn[2] = fminf(mn[2], p2); mx3[2] = fmaxf(mx3[2], p2);
    }
#pragma unroll
    for (int d = 0; d < 3; ++d) {
        float v = mx3[d];
#pragma unroll
        for (int o = 32; o > 0; o >>= 1) v = fmaxf(v, __shfl_xor(v, o));
        if (lane == 0) redmm[wave][d] = v;
        float u = mn[d];
#pragma unroll
        for (int o = 32; o > 0; o >>= 1) u = fminf(u, __shfl_xor(u, o));
        if (lane == 0) redmm[wave][4 + d] = u;
    }
    __syncthreads();

    // --- assemble g(201) ---
    if (t < 64) {
        g[t] = comb[t];
        float s = comb[64 + t], sq = comb[128 + t];
        float avg = s * (1.0f / NPTS);
        g[64 + t] = avg;
        float var = (sq - s * avg) / (float)(NPTS - 1);
        g[128 + t] = sqrtf(fmaxf(var, 0.f));
    } else if (t < 73) {
        int j = t - 64;
        if (j < 3) {
            g[192 + j] = eg[9 + j];
        } else if (j < 6) {
            int d = j - 3;
            float fmx = redmm[0][d], fmn = redmm[0][4 + d];
#pragma unroll
            for (int w2 = 1; w2 < 16; ++w2) {
                fmx = fmaxf(fmx, redmm[w2][d]);
                fmn = fminf(fmn, redmm[w2][4 + d]);
            }
            g[195 + d] = fmx - fmn;
        } else {
            g[198 + (j - 6)] = eg[12 + (j - 6)];
        }
    }
    __syncthreads();

    // --- final MLP 201 -> 256 -> 128 -> 256, split-K over waves ---
    // layer 1: 4 slices of ~51 over j in [0,201)
    {
        int p = t >> 8, c = t & 255;
        int j0 = p * 51, j1 = min(201, j0 + 51);
        float a = 0.f;
        for (int j = j0; j < j1; ++j) a = fmaf(g[j], W3[j * 256 + c], a);
        part[p][c] = a;
    }
    __syncthreads();
    if (t < 256) {
        float a = b3[t] + (part[0][t] + part[1][t]) + (part[2][t] + part[3][t]);
        h1[t] = fmaxf(a, 0.f);
    }
    __syncthreads();
    // layer 2: 8 slices of 32 over j in [0,256)
    {
        int p = t >> 7, c = t & 127;
        int j0 = p * 32;
        float a = 0.f;
#pragma unroll
        for (int j = j0; j < j0 + 32; ++j) a = fmaf(h1[j], W4[j * 128 + c], a);
        part[p][c] = a;
    }
    __syncthreads();
    if (t < 128) {
        float a = b4[t];
#pragma unroll
        for (int p = 0; p < 8; ++p) a += part[p][t];
        h2[t] = fmaxf(a, 0.f);
    }
    __syncthreads();
    // layer 3: 4 slices of 32 over j in [0,128)
    {
        int p = t >> 8, c = t & 255;
        int j0 = p * 32;
        float a = 0.f;
#pragma unroll
        for (int j = j0; j < j0 + 32; ++j) a = fmaf(h2[j], W5[j * 256 + c], a);
        part[p][c] = a;
    }
    __syncthreads();
    if (t < 256) {
        float o = b5[t] + (part[0][t] + part[1][t]) + (part[2][t] + part[3][t]);
        out[(size_t)b * 256 + t] = o;
    }
}

extern "C" void kernel_launch(void* const* d_in, const int* in_sizes, int n_in,
                              void* d_out, int out_size, void* d_ws, size_t ws_size,
                              hipStream_t stream) {
    const float* x  = (const float*)d_in[0];
    const float* W1 = (const float*)d_in[1];
    const float* b1 = (const float*)d_in[2];
    const float* W2 = (const float*)d_in[3];
    const float* b2 = (const float*)d_in[4];
    const float* W3 = (const float*)d_in[5];
    const float* b3 = (const float*)d_in[6];
    const float* W4 = (const float*)d_in[7];
    const float* b4 = (const float*)d_in[8];
    const float* W5 = (const float*)d_in[9];
    const float* b5 = (const float*)d_in[10];
    float* out = (float*)d_out;
    float* ws  = (float*)d_ws;

    pass1_kernel<<<dim3(BATCH, P1_CHUNKS), TPB, 0, stream>>>(x, W1, b1, W2, b2, ws);
    mid_kernel<<<dim3(BATCH), MID_TPB, 0, stream>>>(x, W3, b3, W4, b4, W5, b5, ws, out);
}

// Round 7
// 580.966 us; speedup vs baseline: 1.1163x; 1.1163x over previous
//
#include <hip/hip_runtime.h>
#include <math.h>

#define BATCH 256
#define NPTS  16384
#define TPB   256
#define MID_TPB 1024

// pass1 tiling: grid (BATCH, P1_CHUNKS); 4 waves/block; wave handles 512 pts
#define P1_CHUNKS     8
#define P1_PTS_BLOCK  (NPTS / P1_CHUNKS)      // 2048
#define P1_ITERS      8                        // 8 iters x 64 pts = 512 pts/wave

// ---- workspace: per-(batch,chunk) partials, stride 256 floats ----
// [0..63] chMax, [64..127] chSum, [128..191] chSumSq, [192..200] moments
#define PART_STRIDE 256

typedef __bf16 bf16x8  __attribute__((ext_vector_type(8)));
typedef float  floatx4 __attribute__((ext_vector_type(4)));
typedef float  floatx2 __attribute__((ext_vector_type(2)));

// ---------------- pass 1: coord moments + MFMA point-MLP + channel stats ----------------
// A-frag (16x16x32 bf16): A[m = lane&15][k = (lane>>4)*8 + j]
// B-frag:                 B[k = (lane>>4)*8 + j][n = lane&15]
// C/D layout:             col = lane&15, row = (lane>>4)*4 + reg   [m89]
// R12 (post-mortem of R11 spill: __launch_bounds__ 2nd arg is MIN WAVES PER
// EU, not blocks/CU... w=8 forced unified VGPR+AGPR <= 64/wave; allocator
// split 32 arch + 32 acc (VGPR_Count 32!), our ~76-reg live state spilled:
// WRITE_SIZE 1.66MB -> 578MB, pass1 62 -> 505us. BUT Occupancy 34 -> 71%
// proves the w=4 cap WAS the residency limiter — theory stands, budget
// arithmetic was wrong):
//  - NEW (single variable): w=6 -> 24 waves/CU, reg budget 512/6 ~= 85 >=
//    our ~76 (60 arch + ~16 acc) -> no forced spill, 1.5x resident waves
//    vs w=4. Tripwire unchanged: WRITE_SIZE > ~2MB = spill, revert to w=4.
//  - KEPT: rolled depth-1 prefetch (R10), deferred-relu raw max (R10),
//    biasC-as-C-operand (R6), packed add/fma stats (R8), shfl sem
//    broadcast (R6: direct loads regressed).
// NOTE: all arrays constant-indexed (R3 lesson).
// NOTE2 (R5): do NOT fuse the mid phase in via per-block __threadfence()
// election — device-scope fences are L2 writeback/invalidate ops on gfx950
// and serialized the whole dispatch (63 -> 357 us).
__global__ __launch_bounds__(TPB, 6)
void pass1_kernel(const float* __restrict__ x, const float* __restrict__ W1,
                  const float* __restrict__ b1, const float* __restrict__ W2,
                  const float* __restrict__ b2, float* __restrict__ ws) {
    const int b     = blockIdx.x;
    const int chunk = blockIdx.y;
    const int tid   = threadIdx.x;
    const int lane  = tid & 63;
    const int wave  = tid >> 6;
    const int quad  = lane >> 4;
    const int l15   = lane & 15;

    // W2 (32x64) as 4 B-frags (16-channel tiles); bias folded into C frags
    bf16x8  Bf[4];
    floatx4 biasC[4];
#pragma unroll
    for (int t = 0; t < 4; ++t) {
        int n = t * 16 + l15;
#pragma unroll
        for (int j = 0; j < 8; ++j)
            Bf[t][j] = (__bf16)W2[(quad * 8 + j) * 64 + n];
        float bb = b2[n];
        biasC[t] = (floatx4){bb, bb, bb, bb};
    }
    // layer-1 weights for this lane's k-range (k = quad*8 + j), as f32 pairs
    floatx2 w1a2[4], w1b2[4], b1r2[4];
#pragma unroll
    for (int jp = 0; jp < 4; ++jp) {
        int jj = quad * 8 + jp * 2;
        w1a2[jp] = (floatx2){W1[jj],      W1[jj + 1]};
        w1b2[jp] = (floatx2){W1[32 + jj], W1[32 + jj + 1]};
        b1r2[jp] = (floatx2){b1[jj],      b1[jj + 1]};
    }

    const floatx2 zero2 = {0.f, 0.f};
    float   vmaxr[4] = {0.f, 0.f, 0.f, 0.f};   // raw max, init 0 == deferred relu
    floatx2 vsum[4], vsq[4];
#pragma unroll
    for (int t = 0; t < 4; ++t) {
        vsum[t] = zero2;
        vsq[t]  = zero2;
    }
    float mo[9];
#pragma unroll
    for (int j = 0; j < 9; ++j) mo[j] = 0.f;

    const float* xb = x + ((size_t)b * NPTS + (size_t)chunk * P1_PTS_BLOCK) * 5;
    const float* pc = xb + (size_t)wave * (P1_ITERS * 64) * 5 + (size_t)lane * 5;

    // depth-1 rolled software pipeline
    float c0 = pc[0], c1 = pc[1], c2 = pc[2], s0 = pc[3], s1 = pc[4];

#pragma unroll 1
    for (int it = 0; it < P1_ITERS; ++it) {
        // prefetch it+1 (wave-uniform clamp on last iter: harmless re-read)
        const float* pn = pc + ((it < P1_ITERS - 1) ? 320 : 0);
        float n0 = pn[0], n1 = pn[1], n2 = pn[2], n3 = pn[3], n4 = pn[4];

        mo[0] += c0; mo[1] += c1; mo[2] += c2;
        mo[3] = fmaf(c0, c0, mo[3]); mo[4] = fmaf(c0, c1, mo[4]); mo[5] = fmaf(c0, c2, mo[5]);
        mo[6] = fmaf(c1, c1, mo[6]); mo[7] = fmaf(c1, c2, mo[7]); mo[8] = fmaf(c2, c2, mo[8]);

#pragma unroll
        for (int g = 0; g < 4; ++g) {
            int src = g * 16 + l15;
            float gs0 = __shfl(s0, src);
            float gs1 = __shfl(s1, src);
            floatx2 G0 = {gs0, gs0}, G1 = {gs1, gs1};
            bf16x8 Af;
#pragma unroll
            for (int jp = 0; jp < 4; ++jp) {
                floatx2 h = __builtin_elementwise_fma(
                    G0, w1a2[jp], __builtin_elementwise_fma(G1, w1b2[jp], b1r2[jp]));
                h = __builtin_elementwise_max(h, zero2);
                Af[2 * jp]     = (__bf16)h[0];
                Af[2 * jp + 1] = (__bf16)h[1];
            }
#pragma unroll
            for (int t = 0; t < 4; ++t) {
                // D != C: biasC stays live, no per-MFMA C-init movs
                floatx4 D = __builtin_amdgcn_mfma_f32_16x16x32_bf16(Af, Bf[t], biasC[t], 0, 0, 0);
                // raw max chain (v_max3 fusable), relu deferred via init 0
                vmaxr[t] = fmaxf(fmaxf(D[0], D[1]),
                                 fmaxf(fmaxf(D[2], D[3]), vmaxr[t]));
                floatx2 d01 = {D[0], D[1]}, d23 = {D[2], D[3]};
                floatx2 p01 = __builtin_elementwise_max(d01, zero2); // relu for sum/sq
                floatx2 p23 = __builtin_elementwise_max(d23, zero2);
                vsum[t] += p01 + p23;                                // v_pk_add_f32
                vsq[t]   = __builtin_elementwise_fma(p01, p01,       // v_pk_fma_f32
                               __builtin_elementwise_fma(p23, p23, vsq[t]));
            }
        }

        // rotate pipeline registers
        c0 = n0; c1 = n1; c2 = n2; s0 = n3; s1 = n4;
        pc += 320;   // 64 points * 5 floats
    }

    // finalize packed accumulators, then combine quads (lanes sharing l15)
    float vmax[4], vs[4], vq[4];
#pragma unroll
    for (int t = 0; t < 4; ++t) {
        vmax[t] = vmaxr[t];                    // == max over relu'd (init 0)
        vs[t]   = vsum[t][0] + vsum[t][1];
        vq[t]   = vsq[t][0] + vsq[t][1];
        vmax[t] = fmaxf(vmax[t], __shfl_xor(vmax[t], 16));
        vmax[t] = fmaxf(vmax[t], __shfl_xor(vmax[t], 32));
        vs[t] += __shfl_xor(vs[t], 16);
        vs[t] += __shfl_xor(vs[t], 32);
        vq[t] += __shfl_xor(vq[t], 16);
        vq[t] += __shfl_xor(vq[t], 32);
    }
#pragma unroll
    for (int j = 0; j < 9; ++j) {
        float v = mo[j];
#pragma unroll
        for (int o = 32; o > 0; o >>= 1) v += __shfl_xor(v, o);
        mo[j] = v;
    }

    __shared__ float red[4][201];
    if (quad == 0) {
#pragma unroll
        for (int t = 0; t < 4; ++t) {
            red[wave][t * 16 + l15]       = vmax[t];
            red[wave][64 + t * 16 + l15]  = vs[t];
            red[wave][128 + t * 16 + l15] = vq[t];
        }
    }
    if (lane == 0) {
#pragma unroll
        for (int j = 0; j < 9; ++j) red[wave][192 + j] = mo[j];
    }
    __syncthreads();

    // non-atomic partial write: slot (b*P1_CHUNKS + chunk)
    if (tid < 201) {
        float v0 = red[0][tid], v1 = red[1][tid], v2 = red[2][tid], v3 = red[3][tid];
        float r = (tid < 64) ? fmaxf(fmaxf(v0, v1), fmaxf(v2, v3))
                             : (v0 + v1) + (v2 + v3);
        ws[(size_t)(b * P1_CHUNKS + chunk) * PART_STRIDE + tid] = r;
    }
}

// ---------------- fused mid: reduce partials + eigh + extents + final MLP ----------------
// 1024 threads: 16 waves for the latency-bound extents scan; MLP layers use
// split-K partial sums across the extra waves.
__global__ __launch_bounds__(MID_TPB)
void mid_kernel(const float* __restrict__ x,
                const float* __restrict__ W3, const float* __restrict__ b3,
                const float* __restrict__ W4, const float* __restrict__ b4,
                const float* __restrict__ W5, const float* __restrict__ b5,
                const float* __restrict__ ws, float* __restrict__ out) {
    const int b = blockIdx.x, t = threadIdx.x;
    const int lane = t & 63, wave = t >> 6;

    __shared__ float comb[201];
    __shared__ float eg[15];        // [0..8] evecs, [9..11] eig_norm, [12..14] centroid
    __shared__ float redmm[16][8];
    __shared__ float g[224];
    __shared__ float h1[256];
    __shared__ float h2[128];
    __shared__ float part[8][256];  // split-K partial sums

    // --- reduce the 8 per-chunk partials ---
    if (t < 201) {
        const float* base = ws + (size_t)b * P1_CHUNKS * PART_STRIDE + t;
        float acc = base[0];
        if (t < 64) {
#pragma unroll
            for (int i = 1; i < P1_CHUNKS; ++i) acc = fmaxf(acc, base[i * PART_STRIDE]);
        } else {
#pragma unroll
            for (int i = 1; i < P1_CHUNKS; ++i) acc += base[i * PART_STRIDE];
        }
        comb[t] = acc;
    }
    __syncthreads();

    // --- fp32 Jacobi eigh (thread 0) ---
    if (t == 0) {
        const float n = (float)NPTS;
        float mx = comb[192] / n, my = comb[193] / n, mz = comb[194] / n;
        float A[3][3];
        A[0][0] = comb[195] / n - mx * mx; A[0][1] = comb[196] / n - mx * my;
        A[0][2] = comb[197] / n - mx * mz;
        A[1][1] = comb[198] / n - my * my; A[1][2] = comb[199] / n - my * mz;
        A[2][2] = comb[200] / n - mz * mz;
        A[1][0] = A[0][1]; A[2][0] = A[0][2]; A[2][1] = A[1][2];
        float V[3][3] = {{1, 0, 0}, {0, 1, 0}, {0, 0, 1}};
        const int PP[3] = {0, 0, 1};
        const int QQ[3] = {1, 2, 2};
        for (int sweep = 0; sweep < 7; ++sweep) {
            for (int r3 = 0; r3 < 3; ++r3) {
                int p = PP[r3], q = QQ[r3];
                float apq = A[p][q];
                if (fabsf(apq) < 1e-35f) continue;
                float theta = (A[q][q] - A[p][p]) / (2.0f * apq);
                float tt = 1.0f / (fabsf(theta) + sqrtf(fmaf(theta, theta, 1.0f)));
                if (theta < 0.0f) tt = -tt;
                float c = 1.0f / sqrtf(fmaf(tt, tt, 1.0f)), s = tt * c;
                float apq_t = tt * apq;
                A[p][p] -= apq_t;
                A[q][q] += apq_t;
                A[p][q] = A[q][p] = 0.0f;
                for (int r = 0; r < 3; ++r) {
                    if (r != p && r != q) {
                        float arp = A[r][p], arq = A[r][q];
                        A[r][p] = A[p][r] = c * arp - s * arq;
                        A[r][q] = A[q][r] = s * arp + c * arq;
                    }
                    float vrp = V[r][p], vrq = V[r][q];
                    V[r][p] = c * vrp - s * vrq;
                    V[r][q] = s * vrp + c * vrq;
                }
            }
        }
        float w[3] = {A[0][0], A[1][1], A[2][2]};
        int i0 = 0, i1 = 1, i2 = 2, sw;
        if (w[i0] < w[i1]) { sw = i0; i0 = i1; i1 = sw; }
        if (w[i0] < w[i2]) { sw = i0; i0 = i2; i2 = sw; }
        if (w[i1] < w[i2]) { sw = i1; i1 = i2; i2 = sw; }
        int idx[3] = {i0, i1, i2};
        for (int e = 0; e < 3; ++e)
            for (int comp = 0; comp < 3; ++comp)
                eg[e * 3 + comp] = V[comp][idx[e]];
        float sum = w[0] + w[1] + w[2] + 1e-8f;
        for (int e = 0; e < 3; ++e) eg[9 + e] = w[idx[e]] / sum;
        eg[12] = mx; eg[13] = my; eg[14] = mz;
    }
    __syncthreads();

    // --- projection extents over this batch's 16384 points (16 waves) ---
    float e0x = eg[0], e0y = eg[1], e0z = eg[2];
    float e1x = eg[3], e1y = eg[4], e1z = eg[5];
    float e2x = eg[6], e2y = eg[7], e2z = eg[8];
    float cx = eg[12], cy = eg[13], cz = eg[14];

    const float* xb = x + (size_t)b * NPTS * 5;
    float mn[3] = {3.4e38f, 3.4e38f, 3.4e38f};
    float mx3[3] = {-3.4e38f, -3.4e38f, -3.4e38f};
#pragma unroll 4
    for (int i = 0; i < NPTS / MID_TPB; ++i) {
        const float* p = xb + (size_t)(i * MID_TPB + t) * 5;
        float c0 = p[0] - cx, c1 = p[1] - cy, c2 = p[2] - cz;
        float p0 = fmaf(c0, e0x, fmaf(c1, e0y, c2 * e0z));
        float p1 = fmaf(c0, e1x, fmaf(c1, e1y, c2 * e1z));
        float p2 = fmaf(c0, e2x, fmaf(c1, e2y, c2 * e2z));
        mn[0] = fminf(mn[0], p0); mx3[0] = fmaxf(mx3[0], p0);
        mn[1] = fminf(mn[1], p1); mx3[1] = fmaxf(mx3[1], p1);
        mn[2] = fminf(mn[2], p2); mx3[2] = fmaxf(mx3[2], p2);
    }
#pragma unroll
    for (int d = 0; d < 3; ++d) {
        float v = mx3[d];
#pragma unroll
        for (int o = 32; o > 0; o >>= 1) v = fmaxf(v, __shfl_xor(v, o));
        if (lane == 0) redmm[wave][d] = v;
        float u = mn[d];
#pragma unroll
        for (int o = 32; o > 0; o >>= 1) u = fminf(u, __shfl_xor(u, o));
        if (lane == 0) redmm[wave][4 + d] = u;
    }
    __syncthreads();

    // --- assemble g(201) ---
    if (t < 64) {
        g[t] = comb[t];
        float s = comb[64 + t], sq = comb[128 + t];
        float avg = s * (1.0f / NPTS);
        g[64 + t] = avg;
        float var = (sq - s * avg) / (float)(NPTS - 1);
        g[128 + t] = sqrtf(fmaxf(var, 0.f));
    } else if (t < 73) {
        int j = t - 64;
        if (j < 3) {
            g[192 + j] = eg[9 + j];
        } else if (j < 6) {
            int d = j - 3;
            float fmx = redmm[0][d], fmn = redmm[0][4 + d];
#pragma unroll
            for (int w2 = 1; w2 < 16; ++w2) {
                fmx = fmaxf(fmx, redmm[w2][d]);
                fmn = fminf(fmn, redmm[w2][4 + d]);
            }
            g[195 + d] = fmx - fmn;
        } else {
            g[198 + (j - 6)] = eg[12 + (j - 6)];
        }
    }
    __syncthreads();

    // --- final MLP 201 -> 256 -> 128 -> 256, split-K over waves ---
    // layer 1: 4 slices of ~51 over j in [0,201)
    {
        int p = t >> 8, c = t & 255;
        int j0 = p * 51, j1 = min(201, j0 + 51);
        float a = 0.f;
        for (int j = j0; j < j1; ++j) a = fmaf(g[j], W3[j * 256 + c], a);
        part[p][c] = a;
    }
    __syncthreads();
    if (t < 256) {
        float a = b3[t] + (part[0][t] + part[1][t]) + (part[2][t] + part[3][t]);
        h1[t] = fmaxf(a, 0.f);
    }
    __syncthreads();
    // layer 2: 8 slices of 32 over j in [0,256)
    {
        int p = t >> 7, c = t & 127;
        int j0 = p * 32;
        float a = 0.f;
#pragma unroll
        for (int j = j0; j < j0 + 32; ++j) a = fmaf(h1[j], W4[j * 128 + c], a);
        part[p][c] = a;
    }
    __syncthreads();
    if (t < 128) {
        float a = b4[t];
#pragma unroll
        for (int p = 0; p < 8; ++p) a += part[p][t];
        h2[t] = fmaxf(a, 0.f);
    }
    __syncthreads();
    // layer 3: 4 slices of 32 over j in [0,128)
    {
        int p = t >> 8, c = t & 255;
        int j0 = p * 32;
        float a = 0.f;
#pragma unroll
        for (int j = j0; j < j0 + 32; ++j) a = fmaf(h2[j], W5[j * 256 + c], a);
        part[p][c] = a;
    }
    __syncthreads();
    if (t < 256) {
        float o = b5[t] + (part[0][t] + part[1][t]) + (part[2][t] + part[3][t]);
        out[(size_t)b * 256 + t] = o;
    }
}

extern "C" void kernel_launch(void* const* d_in, const int* in_sizes, int n_in,
                              void* d_out, int out_size, void* d_ws, size_t ws_size,
                              hipStream_t stream) {
    const float* x  = (const float*)d_in[0];
    const float* W1 = (const float*)d_in[1];
    const float* b1 = (const float*)d_in[2];
    const float* W2 = (const float*)d_in[3];
    const float* b2 = (const float*)d_in[4];
    const float* W3 = (const float*)d_in[5];
    const float* b3 = (const float*)d_in[6];
    const float* W4 = (const float*)d_in[7];
    const float* b4 = (const float*)d_in[8];
    const float* W5 = (const float*)d_in[9];
    const float* b5 = (const float*)d_in[10];
    float* out = (float*)d_out;
    float* ws  = (float*)d_ws;

    pass1_kernel<<<dim3(BATCH, P1_CHUNKS), TPB, 0, stream>>>(x, W1, b1, W2, b2, ws);
    mid_kernel<<<dim3(BATCH), MID_TPB, 0, stream>>>(x, W3, b3, W4, b4, W5, b5, ws, out);
}

// Round 9
// 212.522 us; speedup vs baseline: 3.0517x; 2.7337x over previous
//
#include <hip/hip_runtime.h>
#include <math.h>

#define BATCH 256
#define NPTS  16384
#define TPB   256
#define MID_TPB 1024

// pass1 tiling: grid (BATCH, P1_CHUNKS); 4 waves/block; wave handles 512 pts
#define P1_CHUNKS     8
#define P1_PTS_BLOCK  (NPTS / P1_CHUNKS)      // 2048
#define P1_ITERS      8                        // 8 iters x 64 pts = 512 pts/wave

// ---- workspace: per-(batch,chunk) partials, stride 256 floats ----
// [0..63] chMax, [64..127] chSum, [128..191] chSumSq, [192..200] moments
#define PART_STRIDE 256

typedef __bf16 bf16x8  __attribute__((ext_vector_type(8)));
typedef float  floatx4 __attribute__((ext_vector_type(4)));
typedef float  floatx2 __attribute__((ext_vector_type(2)));

// ---------------- pass 1: coord moments + MFMA point-MLP + channel stats ----------------
// A-frag (16x16x32 bf16): A[m = lane&15][k = (lane>>4)*8 + j]
// B-frag:                 B[k = (lane>>4)*8 + j][n = lane&15]
// C/D layout:             col = lane&15, row = (lane>>4)*4 + reg   [m89]
// R14 == R13 resubmitted (R13 bench died on container acquisition, never ran).
// R13 (post-mortem R11/R12: constrained launch_bounds budgets make the
// backend split arch/acc evenly (VGPR_Count 32 @w=8, 40 @w=6) -> our ~60
// arch live values spill (WRITE_SIZE 578/691 MB). Kernel's true footprint
// ~120 regs/wave -> residency pinned at ~16 waves/CU in the 64-128 band.
// Occupancy attack CLOSED; revert to w=4 (proven 62us)):
//  - NEW: shfl chain -> wave-private LDS broadcast. Lane stashes own
//    (s0,s1) once (ds_write_b64, 2-way write alias = free [m136]); all 4
//    groups' sem read up-front into gsem[4] (4x ds_read_b64, same-address
//    4-lane broadcast + 16 distinct banks = conflict-free) -> ONE lgkm
//    window/iter instead of 4-8 bpermute stalls. Moments placed between
//    write and reads to hide write latency. No barrier needed: wave-
//    private slice, single-wave RAW ordered by compiler lgkmcnt.
//  - KEPT: rolled depth-1 prefetch (R10), deferred-relu raw max (R10),
//    biasC-as-C-operand (R6), packed add/fma stats (R8).
// NOTE: all arrays constant-indexed (R3 lesson). Spill tripwire:
// WRITE_SIZE > ~2MB. Fallback if this regresses (R6-style): exact R10.
// NOTE2 (R5): do NOT fuse the mid phase via per-block __threadfence()
// election — device-scope fences serialized the dispatch (63 -> 357 us).
__global__ __launch_bounds__(TPB, 4)
void pass1_kernel(const float* __restrict__ x, const float* __restrict__ W1,
                  const float* __restrict__ b1, const float* __restrict__ W2,
                  const float* __restrict__ b2, float* __restrict__ ws) {
    const int b     = blockIdx.x;
    const int chunk = blockIdx.y;
    const int tid   = threadIdx.x;
    const int lane  = tid & 63;
    const int wave  = tid >> 6;
    const int quad  = lane >> 4;
    const int l15   = lane & 15;

    __shared__ floatx2 sem_lds[4][64];   // [wave][pt] = 2KB, wave-private

    // W2 (32x64) as 4 B-frags (16-channel tiles); bias folded into C frags
    bf16x8  Bf[4];
    floatx4 biasC[4];
#pragma unroll
    for (int t = 0; t < 4; ++t) {
        int n = t * 16 + l15;
#pragma unroll
        for (int j = 0; j < 8; ++j)
            Bf[t][j] = (__bf16)W2[(quad * 8 + j) * 64 + n];
        float bb = b2[n];
        biasC[t] = (floatx4){bb, bb, bb, bb};
    }
    // layer-1 weights for this lane's k-range (k = quad*8 + j), as f32 pairs
    floatx2 w1a2[4], w1b2[4], b1r2[4];
#pragma unroll
    for (int jp = 0; jp < 4; ++jp) {
        int jj = quad * 8 + jp * 2;
        w1a2[jp] = (floatx2){W1[jj],      W1[jj + 1]};
        w1b2[jp] = (floatx2){W1[32 + jj], W1[32 + jj + 1]};
        b1r2[jp] = (floatx2){b1[jj],      b1[jj + 1]};
    }

    const floatx2 zero2 = {0.f, 0.f};
    float   vmaxr[4] = {0.f, 0.f, 0.f, 0.f};   // raw max, init 0 == deferred relu
    floatx2 vsum[4], vsq[4];
#pragma unroll
    for (int t = 0; t < 4; ++t) {
        vsum[t] = zero2;
        vsq[t]  = zero2;
    }
    float mo[9];
#pragma unroll
    for (int j = 0; j < 9; ++j) mo[j] = 0.f;

    const float* xb = x + ((size_t)b * NPTS + (size_t)chunk * P1_PTS_BLOCK) * 5;
    const float* pc = xb + (size_t)wave * (P1_ITERS * 64) * 5 + (size_t)lane * 5;

    // depth-1 rolled software pipeline
    float c0 = pc[0], c1 = pc[1], c2 = pc[2], s0 = pc[3], s1 = pc[4];

#pragma unroll 1
    for (int it = 0; it < P1_ITERS; ++it) {
        // prefetch it+1 (wave-uniform clamp on last iter: harmless re-read)
        const float* pn = pc + ((it < P1_ITERS - 1) ? 320 : 0);
        float n0 = pn[0], n1 = pn[1], n2 = pn[2], n3 = pn[3], n4 = pn[4];

        // stash own sem for this iter's broadcast
        sem_lds[wave][lane] = (floatx2){s0, s1};

        // moments (independent VALU — hides the ds_write latency)
        mo[0] += c0; mo[1] += c1; mo[2] += c2;
        mo[3] = fmaf(c0, c0, mo[3]); mo[4] = fmaf(c0, c1, mo[4]); mo[5] = fmaf(c0, c2, mo[5]);
        mo[6] = fmaf(c1, c1, mo[6]); mo[7] = fmaf(c1, c2, mo[7]); mo[8] = fmaf(c2, c2, mo[8]);

        // all 4 groups' sem up-front: one lgkm window, conflict-free reads
        floatx2 gsem[4];
#pragma unroll
        for (int g = 0; g < 4; ++g)
            gsem[g] = sem_lds[wave][g * 16 + l15];

#pragma unroll
        for (int g = 0; g < 4; ++g) {
            floatx2 G0 = {gsem[g][0], gsem[g][0]};
            floatx2 G1 = {gsem[g][1], gsem[g][1]};
            bf16x8 Af;
#pragma unroll
            for (int jp = 0; jp < 4; ++jp) {
                floatx2 h = __builtin_elementwise_fma(
                    G0, w1a2[jp], __builtin_elementwise_fma(G1, w1b2[jp], b1r2[jp]));
                h = __builtin_elementwise_max(h, zero2);
                Af[2 * jp]     = (__bf16)h[0];
                Af[2 * jp + 1] = (__bf16)h[1];
            }
#pragma unroll
            for (int t = 0; t < 4; ++t) {
                // D != C: biasC stays live, no per-MFMA C-init movs
                floatx4 D = __builtin_amdgcn_mfma_f32_16x16x32_bf16(Af, Bf[t], biasC[t], 0, 0, 0);
                // raw max chain (v_max3 fusable), relu deferred via init 0
                vmaxr[t] = fmaxf(fmaxf(D[0], D[1]),
                                 fmaxf(fmaxf(D[2], D[3]), vmaxr[t]));
                floatx2 d01 = {D[0], D[1]}, d23 = {D[2], D[3]};
                floatx2 p01 = __builtin_elementwise_max(d01, zero2); // relu for sum/sq
                floatx2 p23 = __builtin_elementwise_max(d23, zero2);
                vsum[t] += p01 + p23;                                // v_pk_add_f32
                vsq[t]   = __builtin_elementwise_fma(p01, p01,       // v_pk_fma_f32
                               __builtin_elementwise_fma(p23, p23, vsq[t]));
            }
        }

        // rotate pipeline registers
        c0 = n0; c1 = n1; c2 = n2; s0 = n3; s1 = n4;
        pc += 320;   // 64 points * 5 floats
    }

    // finalize packed accumulators, then combine quads (lanes sharing l15)
    float vmax[4], vs[4], vq[4];
#pragma unroll
    for (int t = 0; t < 4; ++t) {
        vmax[t] = vmaxr[t];                    // == max over relu'd (init 0)
        vs[t]   = vsum[t][0] + vsum[t][1];
        vq[t]   = vsq[t][0] + vsq[t][1];
        vmax[t] = fmaxf(vmax[t], __shfl_xor(vmax[t], 16));
        vmax[t] = fmaxf(vmax[t], __shfl_xor(vmax[t], 32));
        vs[t] += __shfl_xor(vs[t], 16);
        vs[t] += __shfl_xor(vs[t], 32);
        vq[t] += __shfl_xor(vq[t], 16);
        vq[t] += __shfl_xor(vq[t], 32);
    }
#pragma unroll
    for (int j = 0; j < 9; ++j) {
        float v = mo[j];
#pragma unroll
        for (int o = 32; o > 0; o >>= 1) v += __shfl_xor(v, o);
        mo[j] = v;
    }

    __shared__ float red[4][201];
    if (quad == 0) {
#pragma unroll
        for (int t = 0; t < 4; ++t) {
            red[wave][t * 16 + l15]       = vmax[t];
            red[wave][64 + t * 16 + l15]  = vs[t];
            red[wave][128 + t * 16 + l15] = vq[t];
        }
    }
    if (lane == 0) {
#pragma unroll
        for (int j = 0; j < 9; ++j) red[wave][192 + j] = mo[j];
    }
    __syncthreads();

    // non-atomic partial write: slot (b*P1_CHUNKS + chunk)
    if (tid < 201) {
        float v0 = red[0][tid], v1 = red[1][tid], v2 = red[2][tid], v3 = red[3][tid];
        float r = (tid < 64) ? fmaxf(fmaxf(v0, v1), fmaxf(v2, v3))
                             : (v0 + v1) + (v2 + v3);
        ws[(size_t)(b * P1_CHUNKS + chunk) * PART_STRIDE + tid] = r;
    }
}

// ---------------- fused mid: reduce partials + eigh + extents + final MLP ----------------
// 1024 threads: 16 waves for the latency-bound extents scan; MLP layers use
// split-K partial sums across the extra waves.
__global__ __launch_bounds__(MID_TPB)
void mid_kernel(const float* __restrict__ x,
                const float* __restrict__ W3, const float* __restrict__ b3,
                const float* __restrict__ W4, const float* __restrict__ b4,
                const float* __restrict__ W5, const float* __restrict__ b5,
                const float* __restrict__ ws, float* __restrict__ out) {
    const int b = blockIdx.x, t = threadIdx.x;
    const int lane = t & 63, wave = t >> 6;

    __shared__ float comb[201];
    __shared__ float eg[15];        // [0..8] evecs, [9..11] eig_norm, [12..14] centroid
    __shared__ float redmm[16][8];
    __shared__ float g[224];
    __shared__ float h1[256];
    __shared__ float h2[128];
    __shared__ float part[8][256];  // split-K partial sums

    // --- reduce the 8 per-chunk partials ---
    if (t < 201) {
        const float* base = ws + (size_t)b * P1_CHUNKS * PART_STRIDE + t;
        float acc = base[0];
        if (t < 64) {
#pragma unroll
            for (int i = 1; i < P1_CHUNKS; ++i) acc = fmaxf(acc, base[i * PART_STRIDE]);
        } else {
#pragma unroll
            for (int i = 1; i < P1_CHUNKS; ++i) acc += base[i * PART_STRIDE];
        }
        comb[t] = acc;
    }
    __syncthreads();

    // --- fp32 Jacobi eigh (thread 0) ---
    if (t == 0) {
        const float n = (float)NPTS;
        float mx = comb[192] / n, my = comb[193] / n, mz = comb[194] / n;
        float A[3][3];
        A[0][0] = comb[195] / n - mx * mx; A[0][1] = comb[196] / n - mx * my;
        A[0][2] = comb[197] / n - mx * mz;
        A[1][1] = comb[198] / n - my * my; A[1][2] = comb[199] / n - my * mz;
        A[2][2] = comb[200] / n - mz * mz;
        A[1][0] = A[0][1]; A[2][0] = A[0][2]; A[2][1] = A[1][2];
        float V[3][3] = {{1, 0, 0}, {0, 1, 0}, {0, 0, 1}};
        const int PP[3] = {0, 0, 1};
        const int QQ[3] = {1, 2, 2};
        for (int sweep = 0; sweep < 7; ++sweep) {
            for (int r3 = 0; r3 < 3; ++r3) {
                int p = PP[r3], q = QQ[r3];
                float apq = A[p][q];
                if (fabsf(apq) < 1e-35f) continue;
                float theta = (A[q][q] - A[p][p]) / (2.0f * apq);
                float tt = 1.0f / (fabsf(theta) + sqrtf(fmaf(theta, theta, 1.0f)));
                if (theta < 0.0f) tt = -tt;
                float c = 1.0f / sqrtf(fmaf(tt, tt, 1.0f)), s = tt * c;
                float apq_t = tt * apq;
                A[p][p] -= apq_t;
                A[q][q] += apq_t;
                A[p][q] = A[q][p] = 0.0f;
                for (int r = 0; r < 3; ++r) {
                    if (r != p && r != q) {
                        float arp = A[r][p], arq = A[r][q];
                        A[r][p] = A[p][r] = c * arp - s * arq;
                        A[r][q] = A[q][r] = s * arp + c * arq;
                    }
                    float vrp = V[r][p], vrq = V[r][q];
                    V[r][p] = c * vrp - s * vrq;
                    V[r][q] = s * vrp + c * vrq;
                }
            }
        }
        float w[3] = {A[0][0], A[1][1], A[2][2]};
        int i0 = 0, i1 = 1, i2 = 2, sw;
        if (w[i0] < w[i1]) { sw = i0; i0 = i1; i1 = sw; }
        if (w[i0] < w[i2]) { sw = i0; i0 = i2; i2 = sw; }
        if (w[i1] < w[i2]) { sw = i1; i1 = i2; i2 = sw; }
        int idx[3] = {i0, i1, i2};
        for (int e = 0; e < 3; ++e)
            for (int comp = 0; comp < 3; ++comp)
                eg[e * 3 + comp] = V[comp][idx[e]];
        float sum = w[0] + w[1] + w[2] + 1e-8f;
        for (int e = 0; e < 3; ++e) eg[9 + e] = w[idx[e]] / sum;
        eg[12] = mx; eg[13] = my; eg[14] = mz;
    }
    __syncthreads();

    // --- projection extents over this batch's 16384 points (16 waves) ---
    float e0x = eg[0], e0y = eg[1], e0z = eg[2];
    float e1x = eg[3], e1y = eg[4], e1z = eg[5];
    float e2x = eg[6], e2y = eg[7], e2z = eg[8];
    float cx = eg[12], cy = eg[13], cz = eg[14];

    const float* xb = x + (size_t)b * NPTS * 5;
    float mn[3] = {3.4e38f, 3.4e38f, 3.4e38f};
    float mx3[3] = {-3.4e38f, -3.4e38f, -3.4e38f};
#pragma unroll 4
    for (int i = 0; i < NPTS / MID_TPB; ++i) {
        const float* p = xb + (size_t)(i * MID_TPB + t) * 5;
        float c0 = p[0] - cx, c1 = p[1] - cy, c2 = p[2] - cz;
        float p0 = fmaf(c0, e0x, fmaf(c1, e0y, c2 * e0z));
        float p1 = fmaf(c0, e1x, fmaf(c1, e1y, c2 * e1z));
        float p2 = fmaf(c0, e2x, fmaf(c1, e2y, c2 * e2z));
        mn[0] = fminf(mn[0], p0); mx3[0] = fmaxf(mx3[0], p0);
        mn[1] = fminf(mn[1], p1); mx3[1] = fmaxf(mx3[1], p1);
        mn[2] = fminf(mn[2], p2); mx3[2] = fmaxf(mx3[2], p2);
    }
#pragma unroll
    for (int d = 0; d < 3; ++d) {
        float v = mx3[d];
#pragma unroll
        for (int o = 32; o > 0; o >>= 1) v = fmaxf(v, __shfl_xor(v, o));
        if (lane == 0) redmm[wave][d] = v;
        float u = mn[d];
#pragma unroll
        for (int o = 32; o > 0; o >>= 1) u = fminf(u, __shfl_xor(u, o));
        if (lane == 0) redmm[wave][4 + d] = u;
    }
    __syncthreads();

    // --- assemble g(201) ---
    if (t < 64) {
        g[t] = comb[t];
        float s = comb[64 + t], sq = comb[128 + t];
        float avg = s * (1.0f / NPTS);
        g[64 + t] = avg;
        float var = (sq - s * avg) / (float)(NPTS - 1);
        g[128 + t] = sqrtf(fmaxf(var, 0.f));
    } else if (t < 73) {
        int j = t - 64;
        if (j < 3) {
            g[192 + j] = eg[9 + j];
        } else if (j < 6) {
            int d = j - 3;
            float fmx = redmm[0][d], fmn = redmm[0][4 + d];
#pragma unroll
            for (int w2 = 1; w2 < 16; ++w2) {
                fmx = fmaxf(fmx, redmm[w2][d]);
                fmn = fminf(fmn, redmm[w2][4 + d]);
            }
            g[195 + d] = fmx - fmn;
        } else {
            g[198 + (j - 6)] = eg[12 + (j - 6)];
        }
    }
    __syncthreads();

    // --- final MLP 201 -> 256 -> 128 -> 256, split-K over waves ---
    // layer 1: 4 slices of ~51 over j in [0,201)
    {
        int p = t >> 8, c = t & 255;
        int j0 = p * 51, j1 = min(201, j0 + 51);
        float a = 0.f;
        for (int j = j0; j < j1; ++j) a = fmaf(g[j], W3[j * 256 + c], a);
        part[p][c] = a;
    }
    __syncthreads();
    if (t < 256) {
        float a = b3[t] + (part[0][t] + part[1][t]) + (part[2][t] + part[3][t]);
        h1[t] = fmaxf(a, 0.f);
    }
    __syncthreads();
    // layer 2: 8 slices of 32 over j in [0,256)
    {
        int p = t >> 7, c = t & 127;
        int j0 = p * 32;
        float a = 0.f;
#pragma unroll
        for (int j = j0; j < j0 + 32; ++j) a = fmaf(h1[j], W4[j * 128 + c], a);
        part[p][c] = a;
    }
    __syncthreads();
    if (t < 128) {
        float a = b4[t];
#pragma unroll
        for (int p = 0; p < 8; ++p) a += part[p][t];
        h2[t] = fmaxf(a, 0.f);
    }
    __syncthreads();
    // layer 3: 4 slices of 32 over j in [0,128)
    {
        int p = t >> 8, c = t & 255;
        int j0 = p * 32;
        float a = 0.f;
#pragma unroll
        for (int j = j0; j < j0 + 32; ++j) a = fmaf(h2[j], W5[j * 256 + c], a);
        part[p][c] = a;
    }
    __syncthreads();
    if (t < 256) {
        float o = b5[t] + (part[0][t] + part[1][t]) + (part[2][t] + part[3][t]);
        out[(size_t)b * 256 + t] = o;
    }
}

extern "C" void kernel_launch(void* const* d_in, const int* in_sizes, int n_in,
                              void* d_out, int out_size, void* d_ws, size_t ws_size,
                              hipStream_t stream) {
    const float* x  = (const float*)d_in[0];
    const float* W1 = (const float*)d_in[1];
    const float* b1 = (const float*)d_in[2];
    const float* W2 = (const float*)d_in[3];
    const float* b2 = (const float*)d_in[4];
    const float* W3 = (const float*)d_in[5];
    const float* b3 = (const float*)d_in[6];
    const float* W4 = (const float*)d_in[7];
    const float* b4 = (const float*)d_in[8];
    const float* W5 = (const float*)d_in[9];
    const float* b5 = (const float*)d_in[10];
    float* out = (float*)d_out;
    float* ws  = (float*)d_ws;

    pass1_kernel<<<dim3(BATCH, P1_CHUNKS), TPB, 0, stream>>>(x, W1, b1, W2, b2, ws);
    mid_kernel<<<dim3(BATCH), MID_TPB, 0, stream>>>(x, W3, b3, W4, b4, W5, b5, ws, out);
}

// Round 10
// 204.208 us; speedup vs baseline: 3.1759x; 1.0407x over previous
//
#include <hip/hip_runtime.h>
#include <math.h>

#define BATCH 256
#define NPTS  16384
#define TPB   256
#define MID_TPB 1024

// pass1 tiling: grid (BATCH, P1_CHUNKS); 4 waves/block; wave handles 512 pts
#define P1_CHUNKS     8
#define P1_PTS_BLOCK  (NPTS / P1_CHUNKS)      // 2048
#define P1_ITERS      8                        // 8 iters x 64 pts = 512 pts/wave

// ---- workspace: per-(batch,chunk) partials, stride 256 floats ----
// [0..63] chMax, [64..127] chSum, [128..191] chSumSq, [192..200] moments
#define PART_STRIDE 256

typedef __bf16 bf16x8  __attribute__((ext_vector_type(8)));
typedef float  floatx4 __attribute__((ext_vector_type(4)));
typedef float  floatx2 __attribute__((ext_vector_type(2)));

// ---------------- pass 1: coord moments + MFMA point-MLP + channel stats ----------------
// A-frag (16x16x32 bf16): A[m = lane&15][k = (lane>>4)*8 + j]
// B-frag:                 B[k = (lane>>4)*8 + j][n = lane&15]
// C/D layout:             col = lane&15, row = (lane>>4)*4 + reg   [m89]
// R15: pass1 BYTE-IDENTICAL to R14 (verified 60.5us: LDS broadcast + rolled
// prefetch + deferred-relu + biasC-C-operand + packed stats). pass1 is near
// its structural floor: stats at 2.5 instr/value, A-build at 2 fma/hidden,
// occupancy reg-blocked at ~16 waves/CU (R11/R12). This round probes the
// ~150us constant non-pass1 time via mid_kernel changes only.
// History: R6 biasC (+); R8 packed add/fma (+small); R10 rolled prefetch
// (-3us) + deferred-relu; R11/R12 launch_bounds occupancy attack CLOSED
// (unified-file arch/acc split spills: VGPR 32@w=8, 40@w=6, WRITE 578/691MB);
// R14 wave-private LDS sem broadcast (-1.5us).
// NOTE: all arrays constant-indexed (R3 lesson). Spill tripwire:
// WRITE_SIZE > ~2MB.
// NOTE2 (R5): do NOT fuse the mid phase via per-block __threadfence()
// election — device-scope fences serialized the dispatch (63 -> 357 us).
__global__ __launch_bounds__(TPB, 4)
void pass1_kernel(const float* __restrict__ x, const float* __restrict__ W1,
                  const float* __restrict__ b1, const float* __restrict__ W2,
                  const float* __restrict__ b2, float* __restrict__ ws) {
    const int b     = blockIdx.x;
    const int chunk = blockIdx.y;
    const int tid   = threadIdx.x;
    const int lane  = tid & 63;
    const int wave  = tid >> 6;
    const int quad  = lane >> 4;
    const int l15   = lane & 15;

    __shared__ floatx2 sem_lds[4][64];   // [wave][pt] = 2KB, wave-private

    // W2 (32x64) as 4 B-frags (16-channel tiles); bias folded into C frags
    bf16x8  Bf[4];
    floatx4 biasC[4];
#pragma unroll
    for (int t = 0; t < 4; ++t) {
        int n = t * 16 + l15;
#pragma unroll
        for (int j = 0; j < 8; ++j)
            Bf[t][j] = (__bf16)W2[(quad * 8 + j) * 64 + n];
        float bb = b2[n];
        biasC[t] = (floatx4){bb, bb, bb, bb};
    }
    // layer-1 weights for this lane's k-range (k = quad*8 + j), as f32 pairs
    floatx2 w1a2[4], w1b2[4], b1r2[4];
#pragma unroll
    for (int jp = 0; jp < 4; ++jp) {
        int jj = quad * 8 + jp * 2;
        w1a2[jp] = (floatx2){W1[jj],      W1[jj + 1]};
        w1b2[jp] = (floatx2){W1[32 + jj], W1[32 + jj + 1]};
        b1r2[jp] = (floatx2){b1[jj],      b1[jj + 1]};
    }

    const floatx2 zero2 = {0.f, 0.f};
    float   vmaxr[4] = {0.f, 0.f, 0.f, 0.f};   // raw max, init 0 == deferred relu
    floatx2 vsum[4], vsq[4];
#pragma unroll
    for (int t = 0; t < 4; ++t) {
        vsum[t] = zero2;
        vsq[t]  = zero2;
    }
    float mo[9];
#pragma unroll
    for (int j = 0; j < 9; ++j) mo[j] = 0.f;

    const float* xb = x + ((size_t)b * NPTS + (size_t)chunk * P1_PTS_BLOCK) * 5;
    const float* pc = xb + (size_t)wave * (P1_ITERS * 64) * 5 + (size_t)lane * 5;

    // depth-1 rolled software pipeline
    float c0 = pc[0], c1 = pc[1], c2 = pc[2], s0 = pc[3], s1 = pc[4];

#pragma unroll 1
    for (int it = 0; it < P1_ITERS; ++it) {
        // prefetch it+1 (wave-uniform clamp on last iter: harmless re-read)
        const float* pn = pc + ((it < P1_ITERS - 1) ? 320 : 0);
        float n0 = pn[0], n1 = pn[1], n2 = pn[2], n3 = pn[3], n4 = pn[4];

        // stash own sem for this iter's broadcast
        sem_lds[wave][lane] = (floatx2){s0, s1};

        // moments (independent VALU — hides the ds_write latency)
        mo[0] += c0; mo[1] += c1; mo[2] += c2;
        mo[3] = fmaf(c0, c0, mo[3]); mo[4] = fmaf(c0, c1, mo[4]); mo[5] = fmaf(c0, c2, mo[5]);
        mo[6] = fmaf(c1, c1, mo[6]); mo[7] = fmaf(c1, c2, mo[7]); mo[8] = fmaf(c2, c2, mo[8]);

        // all 4 groups' sem up-front: one lgkm window, conflict-free reads
        floatx2 gsem[4];
#pragma unroll
        for (int g = 0; g < 4; ++g)
            gsem[g] = sem_lds[wave][g * 16 + l15];

#pragma unroll
        for (int g = 0; g < 4; ++g) {
            floatx2 G0 = {gsem[g][0], gsem[g][0]};
            floatx2 G1 = {gsem[g][1], gsem[g][1]};
            bf16x8 Af;
#pragma unroll
            for (int jp = 0; jp < 4; ++jp) {
                floatx2 h = __builtin_elementwise_fma(
                    G0, w1a2[jp], __builtin_elementwise_fma(G1, w1b2[jp], b1r2[jp]));
                h = __builtin_elementwise_max(h, zero2);
                Af[2 * jp]     = (__bf16)h[0];
                Af[2 * jp + 1] = (__bf16)h[1];
            }
#pragma unroll
            for (int t = 0; t < 4; ++t) {
                // D != C: biasC stays live, no per-MFMA C-init movs
                floatx4 D = __builtin_amdgcn_mfma_f32_16x16x32_bf16(Af, Bf[t], biasC[t], 0, 0, 0);
                // raw max chain (v_max3 fusable), relu deferred via init 0
                vmaxr[t] = fmaxf(fmaxf(D[0], D[1]),
                                 fmaxf(fmaxf(D[2], D[3]), vmaxr[t]));
                floatx2 d01 = {D[0], D[1]}, d23 = {D[2], D[3]};
                floatx2 p01 = __builtin_elementwise_max(d01, zero2); // relu for sum/sq
                floatx2 p23 = __builtin_elementwise_max(d23, zero2);
                vsum[t] += p01 + p23;                                // v_pk_add_f32
                vsq[t]   = __builtin_elementwise_fma(p01, p01,       // v_pk_fma_f32
                               __builtin_elementwise_fma(p23, p23, vsq[t]));
            }
        }

        // rotate pipeline registers
        c0 = n0; c1 = n1; c2 = n2; s0 = n3; s1 = n4;
        pc += 320;   // 64 points * 5 floats
    }

    // finalize packed accumulators, then combine quads (lanes sharing l15)
    float vmax[4], vs[4], vq[4];
#pragma unroll
    for (int t = 0; t < 4; ++t) {
        vmax[t] = vmaxr[t];                    // == max over relu'd (init 0)
        vs[t]   = vsum[t][0] + vsum[t][1];
        vq[t]   = vsq[t][0] + vsq[t][1];
        vmax[t] = fmaxf(vmax[t], __shfl_xor(vmax[t], 16));
        vmax[t] = fmaxf(vmax[t], __shfl_xor(vmax[t], 32));
        vs[t] += __shfl_xor(vs[t], 16);
        vs[t] += __shfl_xor(vs[t], 32);
        vq[t] += __shfl_xor(vq[t], 16);
        vq[t] += __shfl_xor(vq[t], 32);
    }
#pragma unroll
    for (int j = 0; j < 9; ++j) {
        float v = mo[j];
#pragma unroll
        for (int o = 32; o > 0; o >>= 1) v += __shfl_xor(v, o);
        mo[j] = v;
    }

    __shared__ float red[4][201];
    if (quad == 0) {
#pragma unroll
        for (int t = 0; t < 4; ++t) {
            red[wave][t * 16 + l15]       = vmax[t];
            red[wave][64 + t * 16 + l15]  = vs[t];
            red[wave][128 + t * 16 + l15] = vq[t];
        }
    }
    if (lane == 0) {
#pragma unroll
        for (int j = 0; j < 9; ++j) red[wave][192 + j] = mo[j];
    }
    __syncthreads();

    // non-atomic partial write: slot (b*P1_CHUNKS + chunk)
    if (tid < 201) {
        float v0 = red[0][tid], v1 = red[1][tid], v2 = red[2][tid], v3 = red[3][tid];
        float r = (tid < 64) ? fmaxf(fmaxf(v0, v1), fmaxf(v2, v3))
                             : (v0 + v1) + (v2 + v3);
        ws[(size_t)(b * P1_CHUNKS + chunk) * PART_STRIDE + tid] = r;
    }
}

// ---------------- fused mid: reduce partials + eigh + extents + final MLP ----------------
// R15 probe: (1) eigh computed redundantly by ALL threads in registers
// (wave-uniform branches; removes the t==0 serial phase, the eg[] LDS
// round-trip, and one __syncthreads). Runtime eigenvector-column selects
// rewritten as cndmask ternaries (rule-#20: no runtime-indexed register
// arrays -> no scratch). (2) extents scan unroll 8 (2x loads in flight).
__global__ __launch_bounds__(MID_TPB)
void mid_kernel(const float* __restrict__ x,
                const float* __restrict__ W3, const float* __restrict__ b3,
                const float* __restrict__ W4, const float* __restrict__ b4,
                const float* __restrict__ W5, const float* __restrict__ b5,
                const float* __restrict__ ws, float* __restrict__ out) {
    const int b = blockIdx.x, t = threadIdx.x;
    const int lane = t & 63, wave = t >> 6;

    __shared__ float comb[201];
    __shared__ float redmm[16][8];
    __shared__ float g[224];
    __shared__ float h1[256];
    __shared__ float h2[128];
    __shared__ float part[8][256];  // split-K partial sums

    // --- reduce the 8 per-chunk partials ---
    if (t < 201) {
        const float* base = ws + (size_t)b * P1_CHUNKS * PART_STRIDE + t;
        float acc = base[0];
        if (t < 64) {
#pragma unroll
            for (int i = 1; i < P1_CHUNKS; ++i) acc = fmaxf(acc, base[i * PART_STRIDE]);
        } else {
#pragma unroll
            for (int i = 1; i < P1_CHUNKS; ++i) acc += base[i * PART_STRIDE];
        }
        comb[t] = acc;
    }
    __syncthreads();

    // --- all-thread fp32 Jacobi eigh (uniform data => uniform branches) ---
    const float nin = 1.0f / (float)NPTS;
    const float cx = comb[192] * nin, cy = comb[193] * nin, cz = comb[194] * nin;
    float A[3][3];
    A[0][0] = comb[195] * nin - cx * cx; A[0][1] = comb[196] * nin - cx * cy;
    A[0][2] = comb[197] * nin - cx * cz;
    A[1][1] = comb[198] * nin - cy * cy; A[1][2] = comb[199] * nin - cy * cz;
    A[2][2] = comb[200] * nin - cz * cz;
    A[1][0] = A[0][1]; A[2][0] = A[0][2]; A[2][1] = A[1][2];
    float V[3][3] = {{1, 0, 0}, {0, 1, 0}, {0, 0, 1}};
    {
        const int PP[3] = {0, 0, 1};
        const int QQ[3] = {1, 2, 2};
        for (int sweep = 0; sweep < 7; ++sweep) {
#pragma unroll
            for (int r3 = 0; r3 < 3; ++r3) {
                int p = PP[r3], q = QQ[r3];
                float apq = A[p][q];
                if (fabsf(apq) < 1e-35f) continue;
                float theta = (A[q][q] - A[p][p]) / (2.0f * apq);
                float tt = 1.0f / (fabsf(theta) + sqrtf(fmaf(theta, theta, 1.0f)));
                if (theta < 0.0f) tt = -tt;
                float c = 1.0f / sqrtf(fmaf(tt, tt, 1.0f)), s = tt * c;
                float apq_t = tt * apq;
                A[p][p] -= apq_t;
                A[q][q] += apq_t;
                A[p][q] = A[q][p] = 0.0f;
#pragma unroll
                for (int r = 0; r < 3; ++r) {
                    if (r != p && r != q) {
                        float arp = A[r][p], arq = A[r][q];
                        A[r][p] = A[p][r] = c * arp - s * arq;
                        A[r][q] = A[q][r] = s * arp + c * arq;
                    }
                    float vrp = V[r][p], vrq = V[r][q];
                    V[r][p] = c * vrp - s * vrq;
                    V[r][q] = s * vrp + c * vrq;
                }
            }
        }
    }
    float w0 = A[0][0], w1v = A[1][1], w2v = A[2][2];
    // sort eigenvalue indices descending (scalar ints, no arrays)
    int i0 = 0, i1 = 1, i2 = 2, sw;
    {
        float wa = w0, wb = w1v, wc = w2v, swf;
        if (wa < wb) { sw = i0; i0 = i1; i1 = sw; swf = wa; wa = wb; wb = swf; }
        if (wa < wc) { sw = i0; i0 = i2; i2 = sw; swf = wa; wa = wc; wc = swf; }
        if (wb < wc) { sw = i1; i1 = i2; i2 = sw; swf = wb; wb = wc; wc = swf; }
    }
    // eigenvector columns via cndmask selects (no runtime register indexing)
#define SEL3(a0, a1, a2, id) ((id) == 0 ? (a0) : ((id) == 1 ? (a1) : (a2)))
    const float e0x = SEL3(V[0][0], V[0][1], V[0][2], i0);
    const float e0y = SEL3(V[1][0], V[1][1], V[1][2], i0);
    const float e0z = SEL3(V[2][0], V[2][1], V[2][2], i0);
    const float e1x = SEL3(V[0][0], V[0][1], V[0][2], i1);
    const float e1y = SEL3(V[1][0], V[1][1], V[1][2], i1);
    const float e1z = SEL3(V[2][0], V[2][1], V[2][2], i1);
    const float e2x = SEL3(V[0][0], V[0][1], V[0][2], i2);
    const float e2y = SEL3(V[1][0], V[1][1], V[1][2], i2);
    const float e2z = SEL3(V[2][0], V[2][1], V[2][2], i2);
    const float esum = w0 + w1v + w2v + 1e-8f;
    const float ena = SEL3(w0, w1v, w2v, i0) / esum;
    const float enb = SEL3(w0, w1v, w2v, i1) / esum;
    const float enc = SEL3(w0, w1v, w2v, i2) / esum;
#undef SEL3
    // no barrier needed: every thread holds eg in registers

    // --- projection extents over this batch's 16384 points (16 waves) ---
    const float* xb = x + (size_t)b * NPTS * 5;
    float mn[3] = {3.4e38f, 3.4e38f, 3.4e38f};
    float mx3[3] = {-3.4e38f, -3.4e38f, -3.4e38f};
#pragma unroll 8
    for (int i = 0; i < NPTS / MID_TPB; ++i) {
        const float* p = xb + (size_t)(i * MID_TPB + t) * 5;
        float c0 = p[0] - cx, c1 = p[1] - cy, c2 = p[2] - cz;
        float p0 = fmaf(c0, e0x, fmaf(c1, e0y, c2 * e0z));
        float p1 = fmaf(c0, e1x, fmaf(c1, e1y, c2 * e1z));
        float p2 = fmaf(c0, e2x, fmaf(c1, e2y, c2 * e2z));
        mn[0] = fminf(mn[0], p0); mx3[0] = fmaxf(mx3[0], p0);
        mn[1] = fminf(mn[1], p1); mx3[1] = fmaxf(mx3[1], p1);
        mn[2] = fminf(mn[2], p2); mx3[2] = fmaxf(mx3[2], p2);
    }
#pragma unroll
    for (int d = 0; d < 3; ++d) {
        float v = mx3[d];
#pragma unroll
        for (int o = 32; o > 0; o >>= 1) v = fmaxf(v, __shfl_xor(v, o));
        if (lane == 0) redmm[wave][d] = v;
        float u = mn[d];
#pragma unroll
        for (int o = 32; o > 0; o >>= 1) u = fminf(u, __shfl_xor(u, o));
        if (lane == 0) redmm[wave][4 + d] = u;
    }
    __syncthreads();

    // --- assemble g(201) ---
    if (t < 64) {
        g[t] = comb[t];
        float s = comb[64 + t], sq = comb[128 + t];
        float avg = s * (1.0f / NPTS);
        g[64 + t] = avg;
        float var = (sq - s * avg) / (float)(NPTS - 1);
        g[128 + t] = sqrtf(fmaxf(var, 0.f));
    } else if (t < 73) {
        int j = t - 64;
        if (j < 3) {
            g[192 + j] = (j == 0) ? ena : ((j == 1) ? enb : enc);
        } else if (j < 6) {
            int d = j - 3;
            float fmx = redmm[0][d], fmn = redmm[0][4 + d];
#pragma unroll
            for (int w2 = 1; w2 < 16; ++w2) {
                fmx = fmaxf(fmx, redmm[w2][d]);
                fmn = fminf(fmn, redmm[w2][4 + d]);
            }
            g[195 + d] = fmx - fmn;
        } else {
            int d = j - 6;
            g[198 + d] = (d == 0) ? cx : ((d == 1) ? cy : cz);
        }
    }
    __syncthreads();

    // --- final MLP 201 -> 256 -> 128 -> 256, split-K over waves ---
    // layer 1: 4 slices of ~51 over j in [0,201)
    {
        int p = t >> 8, c = t & 255;
        int j0 = p * 51, j1 = min(201, j0 + 51);
        float a = 0.f;
        for (int j = j0; j < j1; ++j) a = fmaf(g[j], W3[j * 256 + c], a);
        part[p][c] = a;
    }
    __syncthreads();
    if (t < 256) {
        float a = b3[t] + (part[0][t] + part[1][t]) + (part[2][t] + part[3][t]);
        h1[t] = fmaxf(a, 0.f);
    }
    __syncthreads();
    // layer 2: 8 slices of 32 over j in [0,256)
    {
        int p = t >> 7, c = t & 127;
        int j0 = p * 32;
        float a = 0.f;
#pragma unroll
        for (int j = j0; j < j0 + 32; ++j) a = fmaf(h1[j], W4[j * 128 + c], a);
        part[p][c] = a;
    }
    __syncthreads();
    if (t < 128) {
        float a = b4[t];
#pragma unroll
        for (int p = 0; p < 8; ++p) a += part[p][t];
        h2[t] = fmaxf(a, 0.f);
    }
    __syncthreads();
    // layer 3: 4 slices of 32 over j in [0,128)
    {
        int p = t >> 8, c = t & 255;
        int j0 = p * 32;
        float a = 0.f;
#pragma unroll
        for (int j = j0; j < j0 + 32; ++j) a = fmaf(h2[j], W5[j * 256 + c], a);
        part[p][c] = a;
    }
    __syncthreads();
    if (t < 256) {
        float o = b5[t] + (part[0][t] + part[1][t]) + (part[2][t] + part[3][t]);
        out[(size_t)b * 256 + t] = o;
    }
}

extern "C" void kernel_launch(void* const* d_in, const int* in_sizes, int n_in,
                              void* d_out, int out_size, void* d_ws, size_t ws_size,
                              hipStream_t stream) {
    const float* x  = (const float*)d_in[0];
    const float* W1 = (const float*)d_in[1];
    const float* b1 = (const float*)d_in[2];
    const float* W2 = (const float*)d_in[3];
    const float* b2 = (const float*)d_in[4];
    const float* W3 = (const float*)d_in[5];
    const float* b3 = (const float*)d_in[6];
    const float* W4 = (const float*)d_in[7];
    const float* b4 = (const float*)d_in[8];
    const float* W5 = (const float*)d_in[9];
    const float* b5 = (const float*)d_in[10];
    float* out = (float*)d_out;
    float* ws  = (float*)d_ws;

    pass1_kernel<<<dim3(BATCH, P1_CHUNKS), TPB, 0, stream>>>(x, W1, b1, W2, b2, ws);
    mid_kernel<<<dim3(BATCH), MID_TPB, 0, stream>>>(x, W3, b3, W4, b4, W5, b5, ws, out);
}